// Round 11
// baseline (299.395 us; speedup 1.0000x reference)
//
#include <hip/hip_runtime.h>
#include <hip/hip_bf16.h>
#include <math.h>

#define BATCH 8
#define NN    2048
#define FIN   512
#define FOUT  256
#define NEG_BIG -9000000000000000.0f

typedef __attribute__((ext_vector_type(8))) short bf16x8;   // 8 bf16 in 4 VGPR
typedef __attribute__((ext_vector_type(4))) float f32x4;    // MFMA accumulator

// HW RNE fp32->bf16 (pairs fuse to v_cvt_pk_bf16_f32); inputs never NaN.
__device__ __forceinline__ unsigned short f2bf(float x) {
    return __bfloat16_as_ushort(__float2bfloat16(x));
}
__device__ __forceinline__ float bf2f(unsigned short h) {
    return __uint_as_float(((unsigned)h) << 16);
}
// async global->LDS, 16B per lane: dest = (wave-uniform base) + lane*16
__device__ __forceinline__ void gload_lds16(const void* g, void* l) {
    __builtin_amdgcn_global_load_lds((const __attribute__((address_space(1))) void*)g,
                                     (__attribute__((address_space(3))) void*)l,
                                     16, 0, 0);
}
__device__ __forceinline__ void lds_barrier() {       // lgkm-only barrier: vmcnt NOT drained
    asm volatile("s_waitcnt lgkmcnt(0)" ::: "memory");
    __builtin_amdgcn_s_barrier();
    asm volatile("" ::: "memory");
}

// ---------------------------------------------------------------------------
// Kernel 0: Wtf_hi/lo = split-bf16 of W in MFMA fragment order.
// ---------------------------------------------------------------------------
__global__ __launch_bounds__(256) void wt_prep(const float* __restrict__ W,
                                               unsigned short* __restrict__ Wtf_hi,
                                               unsigned short* __restrict__ Wtf_lo) {
    const int tg = blockIdx.x * 256 + threadIdx.x;
    const int n  = tg >> 7;
    const int k4 = (tg & 127) * 4;
    unsigned short h[4], lo[4];
    #pragma unroll
    for (int i = 0; i < 4; i++) {
        const float v = W[(size_t)(k4 + i) * FOUT + n];
        h[i]  = f2bf(v);
        lo[i] = f2bf(v - bf2f(h[i]));
    }
    const int ktile = k4 >> 5, ntile = n >> 4;
    const int lane  = ((k4 >> 3) & 3) * 16 + (n & 15);
    const size_t daddr = ((size_t)(ktile * 16 + ntile) * 64 + lane) * 8 + (k4 & 7);
    uint2 ph, pl;
    ph.x = h[0]  | ((unsigned)h[1]  << 16); ph.y = h[2]  | ((unsigned)h[3]  << 16);
    pl.x = lo[0] | ((unsigned)lo[1] << 16); pl.y = lo[2] | ((unsigned)lo[3] << 16);
    *(uint2*)(Wtf_hi + daddr) = ph;
    *(uint2*)(Wtf_lo + daddr) = pl;
}

// ---------------------------------------------------------------------------
// Kernel 1: ht = (x @ W)^T, split-bf16. No LDS in K-loop (direct-global A,
// fragment-ordered B, zero barriers -> compiler pipelines). Fused f/g epilogue
// (fp32 acc, shfl reduce, atomicAdd on zeroed buffers) + LDS-transpose stores.
// ---------------------------------------------------------------------------
__global__ __launch_bounds__(256, 2) void gemm_xw(const float* __restrict__ x,
        const unsigned short* __restrict__ Wtf_hi,
        const unsigned short* __restrict__ Wtf_lo,
        const float* __restrict__ a,
        unsigned short* __restrict__ ht_hi,
        unsigned short* __restrict__ ht_lo,
        float* __restrict__ f, float* __restrict__ g) {
    __shared__ __attribute__((aligned(16))) unsigned short Tr[64][136];
    const int t  = threadIdx.x;
    const int m0 = (blockIdx.x >> 2) * 128;
    const int n0 = (blockIdx.x & 3) * 64;
    const int l  = t & 63, w = t >> 6;
    const int wr = w >> 1, wc = w & 1;
    const int lr = l & 15, lk = l >> 4;

    f32x4 acc[4][2];
    #pragma unroll
    for (int mt = 0; mt < 4; mt++)
        #pragma unroll
        for (int nt = 0; nt < 2; nt++) acc[mt][nt] = (f32x4){0.f,0.f,0.f,0.f};

    const float* xw = x + (size_t)(m0 + wr*64 + lr) * FIN + lk*8;   // lane's A base

    for (int k0 = 0; k0 < FIN; k0 += 32) {
        bf16x8 bh[2], bl[2];
        const size_t fb = ((size_t)((k0 >> 5) * 16 + (n0 >> 4) + wc*2) * 64 + l) * 8;
        #pragma unroll
        for (int nt = 0; nt < 2; nt++) {
            bh[nt] = *(const bf16x8*)(Wtf_hi + fb + (size_t)nt * 512);
            bl[nt] = *(const bf16x8*)(Wtf_lo + fb + (size_t)nt * 512);
        }
        bf16x8 ah[4], al[4];
        #pragma unroll
        for (int mt = 0; mt < 4; mt++) {
            const float4 v0 = *(const float4*)(xw + (size_t)mt*16*FIN + k0);
            const float4 v1 = *(const float4*)(xw + (size_t)mt*16*FIN + k0 + 4);
            const float vv[8] = {v0.x,v0.y,v0.z,v0.w,v1.x,v1.y,v1.z,v1.w};
            #pragma unroll
            for (int e = 0; e < 8; e++) {
                const unsigned short hh = f2bf(vv[e]);
                ah[mt][e] = (short)hh;
                al[mt][e] = (short)f2bf(vv[e] - bf2f(hh));
            }
        }
        #pragma unroll
        for (int nt = 0; nt < 2; nt++)
            #pragma unroll
            for (int mt = 0; mt < 4; mt++)
                acc[mt][nt] = __builtin_amdgcn_mfma_f32_16x16x32_bf16(ah[mt], bh[nt], acc[mt][nt], 0, 0, 0);
        #pragma unroll
        for (int nt = 0; nt < 2; nt++)
            #pragma unroll
            for (int mt = 0; mt < 4; mt++)
                acc[mt][nt] = __builtin_amdgcn_mfma_f32_16x16x32_bf16(ah[mt], bl[nt], acc[mt][nt], 0, 0, 0);
        #pragma unroll
        for (int nt = 0; nt < 2; nt++)
            #pragma unroll
            for (int mt = 0; mt < 4; mt++)
                acc[mt][nt] = __builtin_amdgcn_mfma_f32_16x16x32_bf16(al[mt], bh[nt], acc[mt][nt], 0, 0, 0);
    }

    const int bb  = m0 >> 11;
    const int jj0 = m0 & 2047;

    // ---- fused f/g: per-row partials, reduce over lr, atomicAdd
    {
        const int nA = n0 + wc*32 + lr;
        const float a1A = a[nA],        a1B = a[nA + 16];
        const float a2A = a[FOUT + nA], a2B = a[FOUT + nA + 16];
        #pragma unroll
        for (int mt = 0; mt < 4; mt++) {
            #pragma unroll
            for (int r = 0; r < 4; r++) {
                float fp = acc[mt][0][r] * a1A + acc[mt][1][r] * a1B;
                float gp = acc[mt][0][r] * a2A + acc[mt][1][r] * a2B;
                #pragma unroll
                for (int m = 1; m < 16; m <<= 1) {
                    fp += __shfl_xor(fp, m);
                    gp += __shfl_xor(gp, m);
                }
                if (lr == 0) {
                    const int row = m0 + wr*64 + mt*16 + lk*4 + r;
                    const int jj  = row & 2047;
                    atomicAdd(&f[(size_t)bb * NN + jj], fp);
                    atomicAdd(&g[(size_t)bb * NN + jj], gp);
                }
            }
        }
    }

    // ---- LDS transpose, two passes (hi then lo), coalesced 256B-row stores
    for (int pass = 0; pass < 2; pass++) {
        #pragma unroll
        for (int mt = 0; mt < 4; mt++)
            #pragma unroll
            for (int nt = 0; nt < 2; nt++) {
                const int nl = wc*32 + nt*16 + lr;
                const int ml = wr*64 + mt*16 + lk*4;
                const float vv[4] = {acc[mt][nt].x, acc[mt][nt].y, acc[mt][nt].z, acc[mt][nt].w};
                unsigned short s[4];
                #pragma unroll
                for (int r = 0; r < 4; r++) {
                    const unsigned short hh = f2bf(vv[r]);
                    s[r] = pass ? f2bf(vv[r] - bf2f(hh)) : hh;
                }
                *(unsigned*)&Tr[nl][ml]     = s[0] | ((unsigned)s[1] << 16);
                *(unsigned*)&Tr[nl][ml + 2] = s[2] | ((unsigned)s[3] << 16);
            }
        __syncthreads();
        unsigned short* dst = pass ? ht_lo : ht_hi;
        #pragma unroll
        for (int q = 0; q < 4; q++) {
            const int idx = t + 256*q, row = idx >> 4, c = idx & 15;
            *(uint4*)(dst + ((size_t)(bb * FOUT + n0 + row)) * NN + jj0 + c*8) =
                *(const uint4*)&Tr[row][c*8];
        }
        __syncthreads();
    }
}

// ---------------------------------------------------------------------------
// Kernel 2: fused attention, software-pipelined (MFMA(jt) || phase-A(jt+1)).
// FIX vs r10: PHASE_A() runs BEFORE LOADAG(jt+2) — LOADAG overwrites the
// a0v..g1v registers PHASE_A consumes (r10 read tile jt+2's adj/g for tile
// jt+1 -> absmax 1.92). vmcnt ledger (fixed order), steady state at the wait:
// FIFO = STAGE(jt)[8] + LOADAG(jt+1)[4] + STAGE(jt+1)[8] = 20 -> vmcnt(8)
// drains STAGE(jt) (Hs[buf] ready) + LOADAG(jt+1) (regs ready); STAGE(jt+1)
// stays in flight across both barriers.
// ---------------------------------------------------------------------------
__global__ __launch_bounds__(512, 1) void gat_attn(
        const unsigned short* __restrict__ ht_hi,
        const unsigned short* __restrict__ ht_lo,
        const int* __restrict__ adj,
        const float* __restrict__ f, const float* __restrict__ g,
        float* __restrict__ out) {
    __shared__ __attribute__((aligned(16))) unsigned short Hs_hi[2][16384];
    __shared__ __attribute__((aligned(16))) unsigned short Hs_lo[2][16384];
    __shared__ __attribute__((aligned(16))) unsigned short Ps_hi[4096];
    __shared__ __attribute__((aligned(16))) unsigned short Ps_lo[4096];
    __shared__ __attribute__((aligned(16))) float fac_s[64];
    __shared__ __attribute__((aligned(16))) float l_s[64];

    const int b  = blockIdx.x & 7;
    const int i0 = (blockIdx.x >> 3) * 64;
    const int t  = threadIdx.x;
    const int w  = t >> 6, l = t & 63;
    const int lr = l & 15, lk = l >> 4;
    const int wr = w >> 2, wc = w & 3;
    const int ar = t >> 3, jg = t & 7;

    const unsigned short* hb_hi = ht_hi + (size_t)b * FOUT * NN;
    const unsigned short* hb_lo = ht_lo + (size_t)b * FOUT * NN;
    const int*   adjr = adj + ((size_t)(b * NN + i0 + ar)) * NN + jg * 8;
    const float* gb   = g + b * NN + jg * 8;
    const float  fi   = f[b * NN + i0 + ar];

    float m_r = -INFINITY, l_r = 0.f;
    f32x4 acc[2][4] = {};
    const int slot = w * 4;

    int4 a0v, a1v; float4 g0v, g1v;

    auto STAGE = [&](int jt) {
        const int buf = jt & 1, j0 = jt * 64;
        #pragma unroll
        for (int q = 0; q < 4; q++) {
            const int idx = (slot + q) * 64 + l;
            const int n = idx >> 3, c = idx & 7;
            const int cc = c ^ (n & 7);
            const size_t go = (size_t)n * NN + j0 + cc * 8;
            gload_lds16(hb_hi + go, &Hs_hi[buf][(slot + q) * 512]);
            gload_lds16(hb_lo + go, &Hs_lo[buf][(slot + q) * 512]);
        }
    };
    auto LOADAG = [&](int jt) {
        const size_t jo = (size_t)jt * 64;
        a0v = *(const int4*)(adjr + jo);
        a1v = *(const int4*)(adjr + jo + 4);
        g0v = *(const float4*)(gb + jo);
        g1v = *(const float4*)(gb + jo + 4);
    };
    auto PHASE_A = [&]() {
        float p[8];
        {
            const float v0 = fi + g0v.x, v1 = fi + g0v.y, v2 = fi + g0v.z, v3 = fi + g0v.w;
            const float v4 = fi + g1v.x, v5 = fi + g1v.y, v6 = fi + g1v.z, v7 = fi + g1v.w;
            p[0] = a0v.x > 0 ? (v0 > 0.f ? v0 : 0.2f*v0) : NEG_BIG;
            p[1] = a0v.y > 0 ? (v1 > 0.f ? v1 : 0.2f*v1) : NEG_BIG;
            p[2] = a0v.z > 0 ? (v2 > 0.f ? v2 : 0.2f*v2) : NEG_BIG;
            p[3] = a0v.w > 0 ? (v3 > 0.f ? v3 : 0.2f*v3) : NEG_BIG;
            p[4] = a1v.x > 0 ? (v4 > 0.f ? v4 : 0.2f*v4) : NEG_BIG;
            p[5] = a1v.y > 0 ? (v5 > 0.f ? v5 : 0.2f*v5) : NEG_BIG;
            p[6] = a1v.z > 0 ? (v6 > 0.f ? v6 : 0.2f*v6) : NEG_BIG;
            p[7] = a1v.w > 0 ? (v7 > 0.f ? v7 : 0.2f*v7) : NEG_BIG;
        }
        float mloc = p[0];
        #pragma unroll
        for (int e = 1; e < 8; e++) mloc = fmaxf(mloc, p[e]);
        mloc = fmaxf(mloc, __shfl_xor(mloc, 1));
        mloc = fmaxf(mloc, __shfl_xor(mloc, 2));
        mloc = fmaxf(mloc, __shfl_xor(mloc, 4));
        const float mn = fmaxf(m_r, mloc);
        float rs = 0.f;
        #pragma unroll
        for (int e = 0; e < 8; e++) { p[e] = __expf(p[e] - mn); rs += p[e]; }
        rs += __shfl_xor(rs, 1);
        rs += __shfl_xor(rs, 2);
        rs += __shfl_xor(rs, 4);
        const float fac = __expf(m_r - mn);
        l_r = l_r * fac + rs;
        m_r = mn;
        if (jg == 0) { fac_s[ar] = fac; l_s[ar] = l_r; }
        unsigned hw_[4], lw_[4];
        #pragma unroll
        for (int e = 0; e < 8; e += 2) {
            const unsigned short h0 = f2bf(p[e]),   h1 = f2bf(p[e+1]);
            const unsigned short q0 = f2bf(p[e]   - bf2f(h0));
            const unsigned short q1 = f2bf(p[e+1] - bf2f(h1));
            hw_[e >> 1] = h0 | ((unsigned)h1 << 16);
            lw_[e >> 1] = q0 | ((unsigned)q1 << 16);
        }
        const int cs = (jg ^ (ar & 7)) * 8;
        *(uint4*)&Ps_hi[ar * 64 + cs] = make_uint4(hw_[0], hw_[1], hw_[2], hw_[3]);
        *(uint4*)&Ps_lo[ar * 64 + cs] = make_uint4(lw_[0], lw_[1], lw_[2], lw_[3]);
    };
    auto MFMA_TILE = [&](int buf, const bf16x8 (&ahf)[2][2], const bf16x8 (&alf)[2][2]) {
        #pragma unroll
        for (int kt = 0; kt < 2; kt++) {
            bf16x8 bh[4], bl[4];
            #pragma unroll
            for (int nt = 0; nt < 4; nt++) {
                const int n  = wc*64 + nt*16 + lr;
                const int cs = ((kt*4 + lk) ^ (n & 7)) * 8;
                bh[nt] = *(const bf16x8*)&Hs_hi[buf][n * 64 + cs];
                bl[nt] = *(const bf16x8*)&Hs_lo[buf][n * 64 + cs];
            }
            #pragma unroll
            for (int nt = 0; nt < 4; nt++)
                #pragma unroll
                for (int mt = 0; mt < 2; mt++)
                    acc[mt][nt] = __builtin_amdgcn_mfma_f32_16x16x32_bf16(ahf[mt][kt], bh[nt], acc[mt][nt], 0, 0, 0);
            #pragma unroll
            for (int nt = 0; nt < 4; nt++)
                #pragma unroll
                for (int mt = 0; mt < 2; mt++)
                    acc[mt][nt] = __builtin_amdgcn_mfma_f32_16x16x32_bf16(ahf[mt][kt], bl[nt], acc[mt][nt], 0, 0, 0);
            #pragma unroll
            for (int nt = 0; nt < 4; nt++)
                #pragma unroll
                for (int mt = 0; mt < 2; mt++)
                    acc[mt][nt] = __builtin_amdgcn_mfma_f32_16x16x32_bf16(alf[mt][kt], bh[nt], acc[mt][nt], 0, 0, 0);
        }
    };

    // ---- prologue
    STAGE(0);
    LOADAG(0);                  // compiler's reg wait drains STAGE(0)+LOADAG(0)
    PHASE_A();                  // tile 0 -> Ps, fac_s=0, l_s
    LOADAG(1);                  // for PHASE_A(tile 1) in iter 0
    lds_barrier();              // Ps(0)/fac_s visible

    bf16x8 ahf[2][2], alf[2][2];
    f32x4 fac4[2];

    for (int jt = 0; jt < 31; jt++) {
        const int buf = jt & 1;
        STAGE(jt + 1);                                   // -> Hs[buf^1]
        asm volatile("s_waitcnt vmcnt(8)" ::: "memory"); // drain STAGE(jt)+LOADAG(jt+1)
        __builtin_amdgcn_sched_barrier(0);
        // pre-read fac + P(jt) frags into regs
        #pragma unroll
        for (int mt = 0; mt < 2; mt++) {
            fac4[mt] = *(const f32x4*)&fac_s[wr*32 + mt*16 + lk*4];
            #pragma unroll
            for (int kt = 0; kt < 2; kt++) {
                const int row = wr*32 + mt*16 + lr;
                const int cs  = ((kt*4 + lk) ^ (row & 7)) * 8;
                ahf[mt][kt] = *(const bf16x8*)&Ps_hi[row * 64 + cs];
                alf[mt][kt] = *(const bf16x8*)&Ps_lo[row * 64 + cs];
            }
        }
        lds_barrier();          // all waves done reading Ps/fac -> safe to rewrite
        // merged section: rescale + [PHASE_A(jt+1) VALU || MFMA(jt)] overlap
        #pragma unroll
        for (int mt = 0; mt < 2; mt++)
            #pragma unroll
            for (int nt = 0; nt < 4; nt++) acc[mt][nt] *= fac4[mt];
        PHASE_A();              // tile jt+1 (consumes LOADAG(jt+1) regs) FIRST
        if (jt < 30) LOADAG(jt + 2);   // THEN clobber regs for next tile
        MFMA_TILE(buf, ahf, alf);
        lds_barrier();          // Ps writes visible; Hs[buf] reads done
    }

    // ---- peeled tail jt=31
    {
        asm volatile("s_waitcnt vmcnt(0)" ::: "memory"); // drain STAGE(31)
        __builtin_amdgcn_sched_barrier(0);
        #pragma unroll
        for (int mt = 0; mt < 2; mt++) {
            fac4[mt] = *(const f32x4*)&fac_s[wr*32 + mt*16 + lk*4];
            #pragma unroll
            for (int kt = 0; kt < 2; kt++) {
                const int row = wr*32 + mt*16 + lr;
                const int cs  = ((kt*4 + lk) ^ (row & 7)) * 8;
                ahf[mt][kt] = *(const bf16x8*)&Ps_hi[row * 64 + cs];
                alf[mt][kt] = *(const bf16x8*)&Ps_lo[row * 64 + cs];
            }
        }
        lds_barrier();
        #pragma unroll
        for (int mt = 0; mt < 2; mt++)
            #pragma unroll
            for (int nt = 0; nt < 4; nt++) acc[mt][nt] *= fac4[mt];
        MFMA_TILE(1, ahf, alf);
    }

    // ---- epilogue: normalize, ELU, store
    #pragma unroll
    for (int mt = 0; mt < 2; mt++) {
        const f32x4 lv = *(const f32x4*)&l_s[wr*32 + mt*16 + lk*4];
        const float li[4] = {1.f/lv.x, 1.f/lv.y, 1.f/lv.z, 1.f/lv.w};
        #pragma unroll
        for (int nt = 0; nt < 4; nt++) {
            const int n = wc*64 + nt*16 + lr;
            const float av[4] = {acc[mt][nt].x, acc[mt][nt].y, acc[mt][nt].z, acc[mt][nt].w};
            #pragma unroll
            for (int r = 0; r < 4; r++) {
                float v = av[r] * li[r];
                v = v > 0.f ? v : (__expf(v) - 1.f);
                out[((size_t)(b * NN + i0 + wr*32 + mt*16 + lk*4 + r)) * FOUT + n] = v;
            }
        }
    }
}

// ---------------------------------------------------------------------------
extern "C" void kernel_launch(void* const* d_in, const int* in_sizes, int n_in,
                              void* d_out, int out_size, void* d_ws, size_t ws_size,
                              hipStream_t stream) {
    const float* x   = (const float*)d_in[0];   // (8, 2048, 512)
    const int*   adj = (const int*)  d_in[1];   // (8, 2048, 2048)
    const float* W   = (const float*)d_in[2];   // (512, 256)
    const float* a   = (const float*)d_in[3];   // (512, 1)
    float* outp = (float*)d_out;                // (8, 2048, 256) fp32

    char* ws = (char*)d_ws;
    unsigned short* ht_hi  = (unsigned short*)ws;                      ws += (size_t)BATCH*FOUT*NN*2;
    unsigned short* ht_lo  = (unsigned short*)ws;                      ws += (size_t)BATCH*FOUT*NN*2;
    unsigned short* Wtf_hi = (unsigned short*)ws;                      ws += (size_t)FOUT*FIN*2;
    unsigned short* Wtf_lo = (unsigned short*)ws;                      ws += (size_t)FOUT*FIN*2;
    float* f = (float*)ws;                                             ws += (size_t)BATCH*NN*4;
    float* g = (float*)ws;

    hipMemsetAsync(f, 0, (size_t)2 * BATCH * NN * 4, stream);   // f+g contiguous
    wt_prep <<<128, 256, 0, stream>>>(W, Wtf_hi, Wtf_lo);
    gemm_xw <<<512, 256, 0, stream>>>(x, Wtf_hi, Wtf_lo, a, ht_hi, ht_lo, f, g);
    gat_attn<<<256, 512, 0, stream>>>(ht_hi, ht_lo, adj, f, g, outp);
}